// Round 5
// baseline (836.926 us; speedup 1.0000x reference)
//
#include <hip/hip_runtime.h>
#include <cstddef>
#include <cstdint>

#define LEAKY(x) ((x) > 0.f ? (x) : 0.2f*(x))

typedef _Float16 f16x8  __attribute__((ext_vector_type(8)));
typedef float    f32x16 __attribute__((ext_vector_type(16)));

// ws float-offsets
#define WS_FEATS   0            // 32*64*128 = 262144 floats
#define WS_SCORES  262144       // 2048
#define WS_RES     264192       // 4096
#define WS_W2      268288       // fp16: 2ch*2pl*64*152 = 38912 halfs (19456 float slots)
#define WS_W1P     287744       // 576 floats

// async global->LDS, 16B per lane; LDS dest = wave-uniform base + lane*16
__device__ __forceinline__ void gll16(const void* g, void* l) {
    __builtin_amdgcn_global_load_lds(
        (const __attribute__((address_space(1))) unsigned int*)g,
        (__attribute__((address_space(3))) unsigned int*)l, 16, 0, 0);
}

// ---------------------------------------------------------------------------
// Pre-kernel (16 blocks x 256): pack conv2 weights fp16 hi/lo,
// W2[chunk][plane][co][152], k = tap*16 + ci_in_chunk (k>=144 zero).
// Row stride 152 halfs = 19 granules (odd) -> B-reads cover all 8 LDS slots.
// Also pack conv1 weights [grun][ci][kh][c*3+kw] for uniform s_load.
// ---------------------------------------------------------------------------
__global__ void kPack(const float* __restrict__ c1w, const float* __restrict__ c2w,
                      float* __restrict__ ws)
{
    _Float16* W2 = (_Float16*)(ws + WS_W2);
    float* w1p = ws + WS_W1P;
    const int t = blockIdx.x*256 + threadIdx.x;
    for (int i = t; i < 2*64*152; i += 16*256) {
        int k = i % 152, rest = i / 152;
        int co = rest & 63, c = rest >> 6;
        _Float16 h = (_Float16)0.f, lo = (_Float16)0.f;
        if (k < 144) {
            int tap = k >> 4, cil = k & 15;
            float wv = c2w[(co*32 + c*16 + cil)*9 + tap];
            h  = (_Float16)wv;
            lo = (_Float16)(wv - (float)h);
        }
        W2[((size_t)(c*2 + 0)*64 + co)*152 + k] = h;
        W2[((size_t)(c*2 + 1)*64 + co)*152 + k] = lo;
    }
    if (blockIdx.x == 0) {
        for (int i = threadIdx.x; i < 576; i += 256) {
            int kw = i % 3; int r = i / 3;
            int c = r & 7; r >>= 3;
            int kh = r % 3; r /= 3;
            int ci = r & 1; int grun = r >> 1;
            int co = grun*8 + c;
            w1p[i] = c1w[co*18 + ci*9 + kh*3 + kw];
        }
    }
}

// ---------------------------------------------------------------------------
// Kernel A: per image n (2048 blocks x 1024 thr = 16 waves, 4/SIMD)
//   conv1 fp32 VALU -> x1 NHWC fp16 hi/lo in LDS
//   conv2 implicit-GEMM v_mfma_f32_32x32x16_f16, 2-term split (3 MFMA/tap)
//   GAP -> proj -> scorer MLP -> score (fp32, 8-way K-split epilogue)
// B-chunks + input staged via global_load_lds (async, hidden under conv1).
// ---------------------------------------------------------------------------
__global__ __launch_bounds__(1024, 4) void kA(
    const float* __restrict__ texts, const float* __restrict__ styles,
    const float* __restrict__ c1b, const float* __restrict__ c2b,
    const float* __restrict__ pw,  const float* __restrict__ pb,
    const float* __restrict__ v1w, const float* __restrict__ v1b,
    const float* __restrict__ v2w, const float* __restrict__ v2b,
    const float* __restrict__ v3w, const float* __restrict__ v3b,
    const float* __restrict__ wsro,
    float* __restrict__ feats, float* __restrict__ scores)
{
    __shared__ __align__(16) float    s_in[2][65][64];   // rows 0-63 data, row 64 zero
    __shared__ __align__(16) _Float16 s_x1[2][33*33*16]; // hi, lo
    __shared__ __align__(16) _Float16 s_B[2][64*152];    // hi, lo (one ci-chunk)
    __shared__ float s_part[8][64];
    __shared__ float s_red2[8][128];
    __shared__ float s_gap[64], s_f[128], s_h[128], s_red[2];

    const int n = blockIdx.x, tid = threadIdx.x;
    const int w = tid >> 6, l = tid & 63;

    const char* W2c = (const char*)(wsro + WS_W2);  // 2 chunks x 38912 B
    char* sB = (char*)&s_B[0][0];

    // ---- issue async staging: B chunk 0 (2432 x16B) + both input channels ----
    gll16(W2c + (size_t)tid*16,        sB + (size_t)tid*16);
    gll16(W2c + (size_t)(tid+1024)*16, sB + (size_t)(tid+1024)*16);
    if (tid < 384)  // 6 full waves
        gll16(W2c + (size_t)(tid+2048)*16, sB + (size_t)(tid+2048)*16);
    gll16((const char*)(texts  + (size_t)n*4096) + (size_t)tid*16,
          (char*)&s_in[0][0][0] + (size_t)tid*16);
    gll16((const char*)(styles + (size_t)n*4096) + (size_t)tid*16,
          (char*)&s_in[1][0][0] + (size_t)tid*16);

    // zero pads while loads fly
    if (tid < 64) s_in[0][64][tid] = 0.f;
    else if (tid < 128) s_in[1][64][tid - 64] = 0.f;
    {
        uint32_t* z = (uint32_t*)&s_x1[0][0];
        for (int i = tid; i < 17424; i += 1024) z[i] = 0u;  // both planes
    }
    __syncthreads();   // drains vmcnt: B0 + inputs resident

    f32x16 acc;
    #pragma unroll
    for (int r = 0; r < 16; ++r) acc[r] = 0.f;

    for (int ch = 0; ch < 2; ++ch) {
        if (ch == 1) {  // s_B free (post-barrier); hide B1 under conv1(1)
            gll16(W2c + 38912 + (size_t)tid*16,        sB + (size_t)tid*16);
            gll16(W2c + 38912 + (size_t)(tid+1024)*16, sB + (size_t)(tid+1024)*16);
            if (tid < 384)
                gll16(W2c + 38912 + (size_t)(tid+2048)*16, sB + (size_t)(tid+2048)*16);
        }

        // ---- conv1: c_out [ch*16, ch*16+16), 2 runs x 8 c_out ----
        {
            const int run = tid >> 9;            // wave-uniform
            const int t9  = tid & 511;
            const int coB = ch*16 + run*8;
            float a[2][8];
            #pragma unroll
            for (int c = 0; c < 8; ++c) {
                float b1 = c1b[coB + c];
                a[0][c] = b1; a[1][c] = b1;
            }
            const float* w1pg = wsro + WS_W1P + (ch*2 + run)*144;
            #pragma unroll
            for (int ci = 0; ci < 2; ++ci)
            #pragma unroll
            for (int kh = 0; kh < 3; ++kh) {
                const float* wrow = w1pg + (ci*3 + kh)*24;
                float wv[24];
                #pragma unroll
                for (int q = 0; q < 6; ++q)
                    *(float4*)&wv[q*4] = *(const float4*)&wrow[q*4];  // uniform -> s_load
                #pragma unroll
                for (int p = 0; p < 2; ++p) {
                    const int pos = t9 + p*512, py = pos >> 5, px = pos & 31;
                    const float* row = &s_in[ci][2*py + kh][2*px];
                    float2 i01 = *(const float2*)row;
                    float  i2  = (px < 31) ? row[2] : 0.f;   // SAME right-pad
                    #pragma unroll
                    for (int c = 0; c < 8; ++c)
                        a[p][c] += wv[c*3]*i01.x + wv[c*3+1]*i01.y + wv[c*3+2]*i2;
                }
            }
            #pragma unroll
            for (int p = 0; p < 2; ++p) {
                const int pos = t9 + p*512, py = pos >> 5, px = pos & 31;
                const int xs = px ^ ((px >> 1) & 1);         // granule-slot swizzle
                const int eo = (py*33 + xs)*16 + run*8;
                _Float16 hh[8], ll[8];
                #pragma unroll
                for (int c = 0; c < 8; ++c) {
                    float v = LEAKY(a[p][c]);
                    _Float16 h = (_Float16)v;
                    hh[c] = h; ll[c] = (_Float16)(v - (float)h);
                }
                *(uint4*)&s_x1[0][eo] = *(uint4*)hh;
                *(uint4*)&s_x1[1][eo] = *(uint4*)ll;
            }
        }
        __syncthreads();   // x1 ready; (ch==1) also drains B1

        // ---- conv2: 16 waves = 8 M-tiles x 2 N-halves, 27 MFMA each ----
        {
            const int mt = w >> 1, nh = w & 1;
            const int pos = mt*32 + (l & 31);
            const int py = pos >> 4, px = pos & 15;
            const int hf = l >> 5;
            const int cob = nh*32 + (l & 31);
            #pragma unroll
            for (int tap = 0; tap < 9; ++tap) {
                const int kh = tap/3, kw = tap%3;
                const int xr = 2*px + kw;
                const int xs = xr ^ ((xr >> 1) & 1);
                const int ae = ((2*py + kh)*33 + xs)*16 + hf*8;
                f16x8 Ah = *(const f16x8*)&s_x1[0][ae];
                f16x8 Al = *(const f16x8*)&s_x1[1][ae];
                const int be = cob*152 + tap*16 + hf*8;
                f16x8 Bh = *(const f16x8*)&s_B[0][be];
                f16x8 Bl = *(const f16x8*)&s_B[1][be];
                acc = __builtin_amdgcn_mfma_f32_32x32x16_f16(Ah, Bh, acc, 0, 0, 0);
                acc = __builtin_amdgcn_mfma_f32_32x32x16_f16(Ah, Bl, acc, 0, 0, 0);
                acc = __builtin_amdgcn_mfma_f32_32x32x16_f16(Al, Bh, acc, 0, 0, 0);
            }
        }
        __syncthreads();   // s_B / s_x1 consumed; safe to restage
    }

    // ---- bias + leaky + GAP (sum all acc regs + both lane halves) ----
    {
        const int mt = w >> 1, nh = w & 1;
        const float b2 = c2b[nh*32 + (l & 31)];
        float s = 0.f;
        #pragma unroll
        for (int r = 0; r < 16; ++r) s += LEAKY(acc[r] + b2);
        s += __shfl_xor(s, 32);
        if (l < 32) s_part[mt][nh*32 + l] = s;
    }
    __syncthreads();
    if (tid < 64) {
        float s = 0.f;
        #pragma unroll
        for (int mt = 0; mt < 8; ++mt) s += s_part[mt][tid];
        s_gap[tid] = s * (1.f/256.f);
    }
    __syncthreads();

    // ---- proj + scorer: 128 outputs x 8-way K-split ----
    const int j = tid & 127, ks = tid >> 7;
    {
        float p = 0.f;
        #pragma unroll
        for (int m = ks*8; m < ks*8 + 8; ++m) p += s_gap[m]*pw[m*128 + j];
        s_red2[ks][j] = p;
    }
    __syncthreads();
    if (tid < 128) {
        float a = pb[tid];
        #pragma unroll
        for (int q = 0; q < 8; ++q) a += s_red2[q][tid];
        feats[(size_t)n*128 + tid] = a;
        s_f[tid] = a;
    }
    __syncthreads();
    {
        float p = 0.f;
        #pragma unroll
        for (int m = ks*16; m < ks*16 + 16; ++m) p += s_f[m]*v1w[m*128 + j];
        s_red2[ks][j] = p;
    }
    __syncthreads();
    if (tid < 128) {
        float a = v1b[tid];
        #pragma unroll
        for (int q = 0; q < 8; ++q) a += s_red2[q][tid];
        s_h[tid] = LEAKY(a);
    }
    __syncthreads();
    {
        float p = 0.f;
        #pragma unroll
        for (int m = ks*16; m < ks*16 + 16; ++m) p += s_h[m]*v2w[m*128 + j];
        s_red2[ks][j] = p;
    }
    __syncthreads();
    if (tid < 128) {
        float a = v2b[tid];
        #pragma unroll
        for (int q = 0; q < 8; ++q) a += s_red2[q][tid];
        a = LEAKY(a);
        s_f[tid] = a * v3w[tid];
    }
    __syncthreads();
    if (tid < 128) {
        float p = s_f[tid];
        #pragma unroll
        for (int off = 32; off; off >>= 1) p += __shfl_xor(p, off);
        if ((tid & 63) == 0) s_red[tid >> 6] = p;
    }
    __syncthreads();
    if (tid == 0) scores[n] = tanhf(s_red[0] + s_red[1] + v3b[0]);
}

// ---------------------------------------------------------------------------
// Kernel B: per-batch argmax (first-index tie-break) + gather feats row
// ---------------------------------------------------------------------------
__global__ __launch_bounds__(128) void kArgGather(
    const float* __restrict__ scores, const float* __restrict__ feats,
    float* __restrict__ res)
{
    __shared__ int s_idx;
    const int b = blockIdx.x, tid = threadIdx.x;
    if (tid < 64) {
        float v = scores[b*64 + tid];
        int   i = tid;
        #pragma unroll
        for (int off = 32; off; off >>= 1) {
            float ov = __shfl_xor(v, off);
            int   oi = __shfl_xor(i, off);
            if (ov > v || (ov == v && oi < i)) { v = ov; i = oi; }
        }
        if (tid == 0) s_idx = i;
    }
    __syncthreads();
    const int idx = s_idx;
    res[b*128 + tid] = feats[((size_t)b*64 + idx)*128 + tid];
}

// ---------------------------------------------------------------------------
// Kernel C: decoder (fp32). bid%8 -> same d2 column slice per XCD.
// ---------------------------------------------------------------------------
__global__ __launch_bounds__(512) void kDecode(
    const float* __restrict__ res,
    const float* __restrict__ d1w, const float* __restrict__ d1b,
    const float* __restrict__ d2w, const float* __restrict__ d2b,
    float* __restrict__ out)
{
    __shared__ float s_res[128];
    __shared__ float s_h[512];
    const int bid = blockIdx.x;
    const int b = bid >> 3, ot = bid & 7;
    const int tid = threadIdx.x;

    if (tid < 128) s_res[tid] = res[b*128 + tid];
    __syncthreads();
    {
        float a = d1b[tid];
        #pragma unroll 8
        for (int m = 0; m < 128; ++m) a += s_res[m]*d1w[m*512 + tid];
        s_h[tid] = LEAKY(a);
    }
    __syncthreads();
    const int o = ot*512 + tid;
    float a = d2b[o];
    for (int k = 0; k < 512; k += 4) {
        float4 h4 = *(const float4*)&s_h[k];
        a += h4.x*d2w[(size_t)(k+0)*4096 + o];
        a += h4.y*d2w[(size_t)(k+1)*4096 + o];
        a += h4.z*d2w[(size_t)(k+2)*4096 + o];
        a += h4.w*d2w[(size_t)(k+3)*4096 + o];
    }
    out[(size_t)b*4096 + o] = tanhf(a);
}

// ---------------------------------------------------------------------------
extern "C" void kernel_launch(void* const* d_in, const int* in_sizes, int n_in,
                              void* d_out, int out_size, void* d_ws, size_t ws_size,
                              hipStream_t stream)
{
    const float* texts  = (const float*)d_in[0];
    const float* styles = (const float*)d_in[1];
    const float* c1w = (const float*)d_in[2];
    const float* c1b = (const float*)d_in[3];
    const float* c2w = (const float*)d_in[4];
    const float* c2b = (const float*)d_in[5];
    const float* pw  = (const float*)d_in[6];
    const float* pb  = (const float*)d_in[7];
    const float* v1w = (const float*)d_in[8];
    const float* v1b = (const float*)d_in[9];
    const float* v2w = (const float*)d_in[10];
    const float* v2b = (const float*)d_in[11];
    const float* v3w = (const float*)d_in[12];
    const float* v3b = (const float*)d_in[13];
    const float* d1w = (const float*)d_in[14];
    const float* d1b = (const float*)d_in[15];
    const float* d2w = (const float*)d_in[16];
    const float* d2b = (const float*)d_in[17];

    float* ws     = (float*)d_ws;
    float* feats  = ws + WS_FEATS;
    float* scores = ws + WS_SCORES;
    float* res    = ws + WS_RES;

    kPack<<<dim3(16), dim3(256), 0, stream>>>(c1w, c2w, ws);
    kA<<<dim3(2048), dim3(1024), 0, stream>>>(
        texts, styles, c1b, c2b, pw, pb,
        v1w, v1b, v2w, v2b, v3w, v3b,
        (const float*)ws, feats, scores);
    kArgGather<<<dim3(32), dim3(128), 0, stream>>>(scores, feats, res);
    kDecode<<<dim3(256), dim3(512), 0, stream>>>(res, d1w, d1b, d2w, d2b,
                                                 (float*)d_out);
}